// Round 4
// baseline (270.275 us; speedup 1.0000x reference)
//
#include <hip/hip_runtime.h>
#include <stdint.h>

typedef __attribute__((ext_vector_type(4))) float  floatx4;   // MFMA C/D frag
typedef __attribute__((ext_vector_type(8))) short  shortx8;   // MFMA A/B frag (8 bf16)
typedef __attribute__((ext_vector_type(4))) unsigned short ushortx4;

typedef unsigned int   u32;
typedef unsigned short u16;

#define TILE    128
#define BK      64
#define THREADS 256
#define CHUNK   (TILE * BK)    // 8192 bf16 elems = 16 KB per (tile, ktile) chunk

// ---- bf16 pack: +0x8000 round, take high halves via v_perm ----
__device__ __forceinline__ u32 pack2bf(float f0, float f1) {
    u32 u0 = __builtin_bit_cast(u32, f0) + 0x8000u;
    u32 u1 = __builtin_bit_cast(u32, f1) + 0x8000u;
    return __builtin_amdgcn_perm(u1, u0, 0x07060302u);  // {u1.hi16, u0.hi16}
}

__device__ __forceinline__ unsigned short f2bf(float f) {
    u32 u = __builtin_bit_cast(u32, f);
    u += 0x7FFFu + ((u >> 16) & 1u);
    return (unsigned short)(u >> 16);
}

// ============ prep (grid-stride): x fp32->bf16 AND W int4->bf16, pre-tiled + XOR-swizzled ============
// Image layout: 16B chunk of logical column-chunk c, row r stored at r*64 + (c^(r&7))*8.
__global__ __launch_bounds__(THREADS)
void prep_kernel(const float* __restrict__ x, const int* __restrict__ pw,
                 const float* __restrict__ scale, const int* __restrict__ pzp,
                 u16* __restrict__ At, u16* __restrict__ Bt,
                 int M, int O, int I, int ng, int KT, int lsSeg) {
    const int NT = gridDim.x * THREADS;
    const int t0 = blockIdx.x * THREADS + threadIdx.x;
    const int segsPerRow = I >> 3;

    // ---- x: fp32 -> bf16 ----
    const int Sx = M * segsPerRow;
    for (int s = t0; s < Sx; s += NT) {
        const int row = s >> lsSeg;
        const int cseg = s & (segsPerRow - 1);
        const int kt = cseg >> 3, cp = cseg & 7;
        const int r = row & (TILE - 1), mt = row >> 7;
        const int c = cp ^ (r & 7);
        const float4 v0 = *(const float4*)(x + (size_t)row * I + kt * BK + c * 8);
        const float4 v1 = *(const float4*)(x + (size_t)row * I + kt * BK + c * 8 + 4);
        u32 p[4];
        p[0] = pack2bf(v0.x, v0.y); p[1] = pack2bf(v0.z, v0.w);
        p[2] = pack2bf(v1.x, v1.y); p[3] = pack2bf(v1.z, v1.w);
        *(uint4*)(At + (size_t)(mt * KT + kt) * CHUNK + r * BK + cp * 8) = *(uint4*)p;
    }

    // ---- W: int4 -> bf16 dequant ----
    const int GS = I / ng;
    const int Sw = O * segsPerRow;
    for (int s = t0; s < Sw; s += NT) {
        const int o = s >> lsSeg;
        const int wpos = s & (segsPerRow - 1);
        const int kt = wpos >> 3, cp = wpos & 7;
        const int r = o & (TILE - 1), nt = o >> 7;
        const int c = cp ^ (r & 7);
        const u32 wq = (u32)pw[(size_t)o * segsPerRow + kt * 8 + c];
        const int g = (kt * BK) / GS;
        const float sc = scale[o * ng + g];
        const int zpw = pzp[o * ((ng + 7) >> 3) + (g >> 3)];
        const int zp = (zpw >> ((g & 7) * 4)) & 15;
        const float nzc = -sc * (float)(zp + 128);
        float v[8];
        #pragma unroll
        for (int j = 0; j < 8; j++) {
            u32 tt;
            if (j < 4)       tt = (wq << (16 - 4 * j)) & 0x000F0000u;
            else if (j == 4) tt = wq & 0x000F0000u;
            else             tt = (wq >> (4 * j - 16)) & 0x000F0000u;
            v[j] = __builtin_fmaf(__builtin_bit_cast(float, tt | 0x43000000u), sc, nzc);  // (nib-zp)*s
        }
        u32 p[4];
        p[0] = pack2bf(v[0], v[1]); p[1] = pack2bf(v[2], v[3]);
        p[2] = pack2bf(v[4], v[5]); p[3] = pack2bf(v[6], v[7]);
        *(uint4*)(Bt + (size_t)(nt * KT + kt) * CHUNK + r * BK + cp * 8) = *(uint4*)p;
    }
}

// ======================= main GEMM: double-buffered, fine-vmcnt raw-barrier pipeline =======================
// Distinct __shared__ arrays (never runtime-selected) so the LDS-DMA waitcnt pass can
// disambiguate: ds_read(As0) must not force a wait on in-flight DMA into As1/Bs1.
__global__ __launch_bounds__(THREADS, 2)
void gemm_bf16(const u16* __restrict__ At, const u16* __restrict__ Bt,
               const float* __restrict__ bias, float* __restrict__ out,
               int O, int KT) {
    __shared__ u16 As0[CHUNK];
    __shared__ u16 Bs0[CHUNK];
    __shared__ u16 As1[CHUNK];
    __shared__ u16 Bs1[CHUNK];

    const int tid = threadIdx.x;
    const int nblk_n = O / TILE;
    const int mt = blockIdx.x / nblk_n;
    const int nt = blockIdx.x % nblk_n;
    const int w = tid >> 6, lane = tid & 63;
    const int wm = w >> 1, wn = w & 1;       // 2x2 wave grid, 64x64 per wave
    const int l15 = lane & 15, l4 = lane >> 4;
    const int sw  = l15 & 7;                 // un-swizzle XOR

    floatx4 acc[4][4];
    #pragma unroll
    for (int i = 0; i < 4; i++)
        #pragma unroll
        for (int j = 0; j < 4; j++)
            acc[i][j] = (floatx4){0.f, 0.f, 0.f, 0.f};

#define ISSUE(KTI, AS_, BS_) do {                                                              \
    const u16* ga_ = At + (size_t)(mt * KT + (KTI)) * CHUNK;                                   \
    const u16* gb_ = Bt + (size_t)(nt * KT + (KTI)) * CHUNK;                                   \
    _Pragma("unroll")                                                                          \
    for (int it_ = 0; it_ < 4; it_++) {                                                        \
        const int off_ = (it_ * THREADS + tid) * 8;                                            \
        __builtin_amdgcn_global_load_lds((const __attribute__((address_space(1))) u32*)(ga_ + off_), \
                                         (__attribute__((address_space(3))) u32*)(AS_ + off_), 16, 0, 0); \
        __builtin_amdgcn_global_load_lds((const __attribute__((address_space(1))) u32*)(gb_ + off_), \
                                         (__attribute__((address_space(3))) u32*)(BS_ + off_), 16, 0, 0); \
    }                                                                                          \
} while (0)

#define COMPUTE(AS_, BS_) do {                                                                 \
    _Pragma("unroll")                                                                          \
    for (int ks_ = 0; ks_ < 2; ks_++) {                                                        \
        shortx8 af_[4], bf_[4];                                                                \
        _Pragma("unroll")                                                                      \
        for (int i_ = 0; i_ < 4; i_++)                                                         \
            af_[i_] = *(const shortx8*)(&AS_[(wm * 64 + i_ * 16 + l15) * BK + ((ks_ * 4 + l4) ^ sw) * 8]); \
        _Pragma("unroll")                                                                      \
        for (int j_ = 0; j_ < 4; j_++)                                                         \
            bf_[j_] = *(const shortx8*)(&BS_[(wn * 64 + j_ * 16 + l15) * BK + ((ks_ * 4 + l4) ^ sw) * 8]); \
        _Pragma("unroll")                                                                      \
        for (int i_ = 0; i_ < 4; i_++)                                                         \
            _Pragma("unroll")                                                                  \
            for (int j_ = 0; j_ < 4; j_++)                                                     \
                acc[i_][j_] = __builtin_amdgcn_mfma_f32_16x16x32_bf16(af_[i_], bf_[j_], acc[i_][j_], 0, 0, 0); \
    }                                                                                          \
} while (0)

// pre-compute barrier: own tile-k loads done (8 newest = prefetch stay in flight), then sync
#define WAITBAR8() __asm__ volatile("s_waitcnt vmcnt(8)\n\ts_barrier" ::: "memory")
#define WAITBAR0() __asm__ volatile("s_waitcnt vmcnt(0)\n\ts_barrier" ::: "memory")
// post-compute barrier: all waves done reading this buffer before it is re-targeted
#define ENDBAR()   __asm__ volatile("s_waitcnt lgkmcnt(0)\n\ts_barrier" ::: "memory")

    ISSUE(0, As0, Bs0);
    for (int kt = 0; kt < KT; kt += 2) {
        // even phase: compute kt from buf0, prefetch kt+1 into buf1
        if (kt + 1 < KT) { ISSUE(kt + 1, As1, Bs1); WAITBAR8(); }
        else             { WAITBAR0(); }
        COMPUTE(As0, Bs0);
        ENDBAR();
        if (kt + 1 < KT) {
            // odd phase: compute kt+1 from buf1, prefetch kt+2 into buf0
            if (kt + 2 < KT) { ISSUE(kt + 2, As0, Bs0); WAITBAR8(); }
            else             { WAITBAR0(); }
            COMPUTE(As1, Bs1);
            ENDBAR();
        }
    }

#undef ISSUE
#undef COMPUTE
#undef WAITBAR8
#undef WAITBAR0
#undef ENDBAR

    #pragma unroll
    for (int j = 0; j < 4; j++) {
        int col  = nt * TILE + wn * 64 + j * 16 + l15;
        float bv = bias[col];
        #pragma unroll
        for (int i = 0; i < 4; i++) {
            int rowb = mt * TILE + wm * 64 + i * 16 + l4 * 4;
            #pragma unroll
            for (int r = 0; r < 4; r++)
                out[(size_t)(rowb + r) * O + col] = acc[i][j][r] + bv;
        }
    }
}

// ======================= fallback (round-1 fused kernel) if ws too small =======================
#define LDA 72
__global__ __launch_bounds__(THREADS, 2)
void wql_fused(const float* __restrict__ x, const int* __restrict__ pw,
               const float* __restrict__ scale, const int* __restrict__ pzp,
               const float* __restrict__ bias, float* __restrict__ out,
               int M, int O, int I, int ng)
{
    __shared__ unsigned short As[TILE * LDA];
    __shared__ unsigned short Bs[TILE * LDA];
    const int tid = threadIdx.x;
    const int nblk_n = O / TILE;
    const int mt = blockIdx.x / nblk_n, nt = blockIdx.x % nblk_n;
    const int w = tid >> 6, lane = tid & 63;
    const int wm = w >> 1, wn = w & 1;
    const int l15 = lane & 15, l4 = lane >> 4;
    const int pw_rowlen = I / 8, zp_rowlen = (ng + 7) / 8, GS = I / ng;

    floatx4 acc[4][4];
    #pragma unroll
    for (int i = 0; i < 4; i++)
        #pragma unroll
        for (int j = 0; j < 4; j++) acc[i][j] = (floatx4){0.f, 0.f, 0.f, 0.f};

    const int nk = I / BK;
    for (int kt = 0; kt < nk; kt++) {
        __syncthreads();
        #pragma unroll
        for (int it = 0; it < 8; it++) {
            int f = tid + it * THREADS;
            int row = f >> 4, seg = f & 15;
            const float4 v = *(const float4*)(x + (size_t)(mt * TILE + row) * I + kt * BK + seg * 4);
            ushortx4 b;
            b.x = f2bf(v.x); b.y = f2bf(v.y); b.z = f2bf(v.z); b.w = f2bf(v.w);
            *(ushortx4*)(&As[row * LDA + seg * 4]) = b;
        }
        const int g = (kt * BK) / GS;
        #pragma unroll
        for (int it = 0; it < 4; it++) {
            int e = tid + it * THREADS;
            int row = e >> 3, c = e & 7;
            int o = nt * TILE + row;
            int wq = pw[(size_t)o * pw_rowlen + kt * (BK / 8) + c];
            float s = scale[o * ng + g];
            int zpw = pzp[o * zp_rowlen + (g >> 3)];
            int zp = (zpw >> ((g & 7) * 4)) & 15;
            shortx8 b;
            #pragma unroll
            for (int j = 0; j < 8; j++) {
                int nib = (wq >> (4 * j)) & 15;
                b[j] = (short)f2bf((float)(nib - zp) * s);
            }
            *(shortx8*)(&Bs[row * LDA + c * 8]) = b;
        }
        __syncthreads();
        #pragma unroll
        for (int ks = 0; ks < 2; ks++) {
            shortx8 af[4], bf[4];
            #pragma unroll
            for (int i = 0; i < 4; i++)
                af[i] = *(const shortx8*)(&As[(wm * 64 + i * 16 + l15) * LDA + ks * 32 + l4 * 8]);
            #pragma unroll
            for (int j = 0; j < 4; j++)
                bf[j] = *(const shortx8*)(&Bs[(wn * 64 + j * 16 + l15) * LDA + ks * 32 + l4 * 8]);
            #pragma unroll
            for (int i = 0; i < 4; i++)
                #pragma unroll
                for (int j = 0; j < 4; j++)
                    acc[i][j] = __builtin_amdgcn_mfma_f32_16x16x32_bf16(af[i], bf[j], acc[i][j], 0, 0, 0);
        }
    }
    #pragma unroll
    for (int j = 0; j < 4; j++) {
        int col = nt * TILE + wn * 64 + j * 16 + l15;
        float bv = bias[col];
        #pragma unroll
        for (int i = 0; i < 4; i++) {
            int rowb = mt * TILE + wm * 64 + i * 16 + l4 * 4;
            #pragma unroll
            for (int r = 0; r < 4; r++)
                out[(size_t)(rowb + r) * O + col] = acc[i][j][r] + bv;
        }
    }
}

extern "C" void kernel_launch(void* const* d_in, const int* in_sizes, int n_in,
                              void* d_out, int out_size, void* d_ws, size_t ws_size,
                              hipStream_t stream) {
    const float* x     = (const float*)d_in[0];
    const int*   pw    = (const int*)d_in[1];
    const float* scale = (const float*)d_in[2];
    const int*   pzp   = (const int*)d_in[3];
    const float* bias  = (const float*)d_in[4];
    float*       out   = (float*)d_out;

    const int O  = in_sizes[4];                   // 4096
    const int ng = in_sizes[2] / O;               // 32
    const int I  = (in_sizes[1] / O) * 8;         // 4096
    const int M  = in_sizes[0] / I;               // 4096
    const int KT = I / BK;                        // 64
    int lsSeg = 0; { int v = I >> 3; while ((1 << lsSeg) < v) lsSeg++; }  // log2(I/8)

    const size_t need = ((size_t)M * I + (size_t)O * I) * sizeof(u16);  // 64 MB
    if (ws_size >= need) {
        u16* At = (u16*)d_ws;
        u16* Bt = At + (size_t)M * I;
        prep_kernel<<<dim3(2048), THREADS, 0, stream>>>(x, pw, scale, pzp, At, Bt, M, O, I, ng, KT, lsSeg);
        gemm_bf16<<<dim3((M / TILE) * (O / TILE)), THREADS, 0, stream>>>(At, Bt, bias, out, O, KT);
    } else {
        wql_fused<<<dim3((M / TILE) * (O / TILE)), THREADS, 0, stream>>>(x, pw, scale, pzp, bias, out, M, O, I, ng);
    }
}

// Round 6
// 257.235 us; speedup vs baseline: 1.0507x; 1.0507x over previous
//
#include <hip/hip_runtime.h>
#include <stdint.h>

typedef __attribute__((ext_vector_type(4))) float  floatx4;   // MFMA C/D frag
typedef __attribute__((ext_vector_type(8))) short  shortx8;   // MFMA A/B frag (8 bf16)
typedef __attribute__((ext_vector_type(4))) unsigned short ushortx4;

typedef unsigned int   u32;
typedef unsigned short u16;

#define TILE    128
#define BK      64
#define THREADS 256
#define CHUNK   (TILE * BK)    // 8192 bf16 elems = 16 KB LDS per tile

// ---- bf16 pack: +0x8000 round, take high halves via v_perm ----
__device__ __forceinline__ u32 pack2bf(float f0, float f1) {
    u32 u0 = __builtin_bit_cast(u32, f0) + 0x8000u;
    u32 u1 = __builtin_bit_cast(u32, f1) + 0x8000u;
    return __builtin_amdgcn_perm(u1, u0, 0x07060302u);  // {u1.hi16, u0.hi16}
}

__device__ __forceinline__ unsigned short f2bf(float f) {
    u32 u = __builtin_bit_cast(u32, f);
    u += 0x7FFFu + ((u >> 16) & 1u);
    return (unsigned short)(u >> 16);
}

// ============ prep (grid-stride, fully streaming): linear-in, linear-out ============
// At: x converted fp32->bf16, row-major [M][I].  Bt: W dequantized int4->bf16, row-major [O][I].
__global__ __launch_bounds__(THREADS)
void prep_kernel(const float* __restrict__ x, const int* __restrict__ pw,
                 const float* __restrict__ scale, const int* __restrict__ pzp,
                 u16* __restrict__ At, u16* __restrict__ Bt,
                 int M, int O, int I, int ng, int lsSeg, int lsG) {
    const int NT = gridDim.x * THREADS;
    const int t0 = blockIdx.x * THREADS + threadIdx.x;
    const int segsPerRow = I >> 3;

    // ---- x: fp32 -> bf16, 8 elems (32B in, 16B out) per unit, fully linear ----
    const int Sx = (M * I) >> 3;
    for (int s = t0; s < Sx; s += NT) {
        const float4 v0 = ((const float4*)x)[(size_t)s * 2];
        const float4 v1 = ((const float4*)x)[(size_t)s * 2 + 1];
        u32 p[4];
        p[0] = pack2bf(v0.x, v0.y); p[1] = pack2bf(v0.z, v0.w);
        p[2] = pack2bf(v1.x, v1.y); p[3] = pack2bf(v1.z, v1.w);
        ((uint4*)At)[s] = *(uint4*)p;
    }

    // ---- W: int4 -> bf16 dequant, one int32 word -> 16B out, fully linear ----
    const int Sw = (O * I) >> 3;
    for (int s = t0; s < Sw; s += NT) {
        const u32 wq = (u32)pw[s];
        const int o    = s >> lsSeg;
        const int wcol = s & (segsPerRow - 1);
        const int g    = wcol >> lsG;                 // 16 words per 128-k group
        const float sc = scale[o * ng + g];
        const int zpw  = pzp[o * ((ng + 7) >> 3) + (g >> 3)];
        const int zp   = (zpw >> ((g & 7) * 4)) & 15;
        const float nzc = -sc * (float)(zp + 128);
        float v[8];
        #pragma unroll
        for (int j = 0; j < 8; j++) {
            u32 tt;
            if (j < 4)       tt = (wq << (16 - 4 * j)) & 0x000F0000u;
            else if (j == 4) tt = wq & 0x000F0000u;
            else             tt = (wq >> (4 * j - 16)) & 0x000F0000u;
            v[j] = __builtin_fmaf(__builtin_bit_cast(float, tt | 0x43000000u), sc, nzc);  // (nib-zp)*s
        }
        u32 p[4];
        p[0] = pack2bf(v[0], v[1]); p[1] = pack2bf(v[2], v[3]);
        p[2] = pack2bf(v[4], v[5]); p[3] = pack2bf(v[6], v[7]);
        ((uint4*)Bt)[s] = *(uint4*)p;
    }
}

// ============ main GEMM: round-3 single-buffer structure, swizzle moved into DMA ============
// global_load_lds: LDS dest is lane-linear (required); global source per-lane address
// carries the XOR swizzle, so the LDS image equals round 3's conflict-free layout.
__global__ __launch_bounds__(THREADS, 2)
void gemm_bf16(const u16* __restrict__ At, const u16* __restrict__ Bt,
               const float* __restrict__ bias, float* __restrict__ out,
               int O, int I, int KT) {
    __shared__ u16 As[CHUNK];
    __shared__ u16 Bs[CHUNK];

    const int tid = threadIdx.x;
    const int nblk_n = O / TILE;
    const int mt = blockIdx.x / nblk_n;      // mt-major: A-stripe reuse clusters in time
    const int nt = blockIdx.x % nblk_n;
    const int w = tid >> 6, lane = tid & 63;
    const int wm = w >> 1, wn = w & 1;       // 2x2 wave grid, 64x64 per wave
    const int l15 = lane & 15, l4 = lane >> 4;
    const int sw  = l15 & 7;                 // un-swizzle XOR for frag reads

    // staging map: issue it stages rows it*32..it*32+31; thread t -> row it*32+(t>>3),
    // LDS chunk position t&7, fetching logical chunk (t&7) ^ (row&7). it*32 ≡ 0 (mod 8).
    const int sr = tid >> 3;
    const int sc = (tid & 7) ^ (sr & 7);

    floatx4 acc[4][4];
    #pragma unroll
    for (int i = 0; i < 4; i++)
        #pragma unroll
        for (int j = 0; j < 4; j++)
            acc[i][j] = (floatx4){0.f, 0.f, 0.f, 0.f};

    const u16* gaBase = At + ((size_t)(mt * TILE) + sr) * I + sc * 8;
    const u16* gbBase = Bt + ((size_t)(nt * TILE) + sr) * I + sc * 8;

    for (int kt = 0; kt < KT; kt++) {
        const u16* ga = gaBase + kt * BK;
        const u16* gb = gbBase + kt * BK;
        __syncthreads();                      // previous tile fully consumed
        #pragma unroll
        for (int it = 0; it < 4; it++) {
            const int ldsOff = it * 2048 + tid * 8;      // lane-linear 16B slots
            const size_t gOff = (size_t)(it * 32) * I;
            __builtin_amdgcn_global_load_lds((const __attribute__((address_space(1))) u32*)(ga + gOff),
                                             (__attribute__((address_space(3))) u32*)(As + ldsOff),
                                             16, 0, 0);
            __builtin_amdgcn_global_load_lds((const __attribute__((address_space(1))) u32*)(gb + gOff),
                                             (__attribute__((address_space(3))) u32*)(Bs + ldsOff),
                                             16, 0, 0);
        }
        __syncthreads();                      // vmcnt(0) drain: tiles visible

        #pragma unroll
        for (int ks = 0; ks < 2; ks++) {
            shortx8 af[4], bf[4];
            #pragma unroll
            for (int i = 0; i < 4; i++)
                af[i] = *(const shortx8*)(&As[(wm * 64 + i * 16 + l15) * BK + ((ks * 4 + l4) ^ sw) * 8]);
            #pragma unroll
            for (int j = 0; j < 4; j++)
                bf[j] = *(const shortx8*)(&Bs[(wn * 64 + j * 16 + l15) * BK + ((ks * 4 + l4) ^ sw) * 8]);
            #pragma unroll
            for (int i = 0; i < 4; i++)
                #pragma unroll
                for (int j = 0; j < 4; j++)
                    acc[i][j] = __builtin_amdgcn_mfma_f32_16x16x32_bf16(af[i], bf[j], acc[i][j], 0, 0, 0);
        }
    }

    #pragma unroll
    for (int j = 0; j < 4; j++) {
        int col  = nt * TILE + wn * 64 + j * 16 + l15;
        float bv = bias[col];
        #pragma unroll
        for (int i = 0; i < 4; i++) {
            int rowb = mt * TILE + wm * 64 + i * 16 + l4 * 4;
            #pragma unroll
            for (int r = 0; r < 4; r++)
                out[(size_t)(rowb + r) * O + col] = acc[i][j][r] + bv;
        }
    }
}

// ======================= fallback (round-1 fused kernel) if ws too small =======================
#define LDA 72
__global__ __launch_bounds__(THREADS, 2)
void wql_fused(const float* __restrict__ x, const int* __restrict__ pw,
               const float* __restrict__ scale, const int* __restrict__ pzp,
               const float* __restrict__ bias, float* __restrict__ out,
               int M, int O, int I, int ng)
{
    __shared__ unsigned short As[TILE * LDA];
    __shared__ unsigned short Bs[TILE * LDA];
    const int tid = threadIdx.x;
    const int nblk_n = O / TILE;
    const int mt = blockIdx.x / nblk_n, nt = blockIdx.x % nblk_n;
    const int w = tid >> 6, lane = tid & 63;
    const int wm = w >> 1, wn = w & 1;
    const int l15 = lane & 15, l4 = lane >> 4;
    const int pw_rowlen = I / 8, zp_rowlen = (ng + 7) / 8, GS = I / ng;

    floatx4 acc[4][4];
    #pragma unroll
    for (int i = 0; i < 4; i++)
        #pragma unroll
        for (int j = 0; j < 4; j++) acc[i][j] = (floatx4){0.f, 0.f, 0.f, 0.f};

    const int nk = I / BK;
    for (int kt = 0; kt < nk; kt++) {
        __syncthreads();
        #pragma unroll
        for (int it = 0; it < 8; it++) {
            int f = tid + it * THREADS;
            int row = f >> 4, seg = f & 15;
            const float4 v = *(const float4*)(x + (size_t)(mt * TILE + row) * I + kt * BK + seg * 4);
            ushortx4 b;
            b.x = f2bf(v.x); b.y = f2bf(v.y); b.z = f2bf(v.z); b.w = f2bf(v.w);
            *(ushortx4*)(&As[row * LDA + seg * 4]) = b;
        }
        const int g = (kt * BK) / GS;
        #pragma unroll
        for (int it = 0; it < 4; it++) {
            int e = tid + it * THREADS;
            int row = e >> 3, c = e & 7;
            int o = nt * TILE + row;
            int wq = pw[(size_t)o * pw_rowlen + kt * (BK / 8) + c];
            float s = scale[o * ng + g];
            int zpw = pzp[o * zp_rowlen + (g >> 3)];
            int zp = (zpw >> ((g & 7) * 4)) & 15;
            shortx8 b;
            #pragma unroll
            for (int j = 0; j < 8; j++) {
                int nib = (wq >> (4 * j)) & 15;
                b[j] = (short)f2bf((float)(nib - zp) * s);
            }
            *(shortx8*)(&Bs[row * LDA + c * 8]) = b;
        }
        __syncthreads();
        #pragma unroll
        for (int ks = 0; ks < 2; ks++) {
            shortx8 af[4], bf[4];
            #pragma unroll
            for (int i = 0; i < 4; i++)
                af[i] = *(const shortx8*)(&As[(wm * 64 + i * 16 + l15) * LDA + ks * 32 + l4 * 8]);
            #pragma unroll
            for (int j = 0; j < 4; j++)
                bf[j] = *(const shortx8*)(&Bs[(wn * 64 + j * 16 + l15) * LDA + ks * 32 + l4 * 8]);
            #pragma unroll
            for (int i = 0; i < 4; i++)
                #pragma unroll
                for (int j = 0; j < 4; j++)
                    acc[i][j] = __builtin_amdgcn_mfma_f32_16x16x32_bf16(af[i], bf[j], acc[i][j], 0, 0, 0);
        }
    }
    #pragma unroll
    for (int j = 0; j < 4; j++) {
        int col = nt * TILE + wn * 64 + j * 16 + l15;
        float bv = bias[col];
        #pragma unroll
        for (int i = 0; i < 4; i++) {
            int rowb = mt * TILE + wm * 64 + i * 16 + l4 * 4;
            #pragma unroll
            for (int r = 0; r < 4; r++)
                out[(size_t)(rowb + r) * O + col] = acc[i][j][r] + bv;
        }
    }
}

extern "C" void kernel_launch(void* const* d_in, const int* in_sizes, int n_in,
                              void* d_out, int out_size, void* d_ws, size_t ws_size,
                              hipStream_t stream) {
    const float* x     = (const float*)d_in[0];
    const int*   pw    = (const int*)d_in[1];
    const float* scale = (const float*)d_in[2];
    const int*   pzp   = (const int*)d_in[3];
    const float* bias  = (const float*)d_in[4];
    float*       out   = (float*)d_out;

    const int O  = in_sizes[4];                   // 4096
    const int ng = in_sizes[2] / O;               // 32
    const int I  = (in_sizes[1] / O) * 8;         // 4096
    const int M  = in_sizes[0] / I;               // 4096
    const int KT = I / BK;                        // 64
    int lsSeg = 0; { int v = I >> 3; while ((1 << lsSeg) < v) lsSeg++; }      // log2(I/8)
    int lsG = 0;   { int v = (I / ng) >> 3; while ((1 << lsG) < v) lsG++; }   // log2(GS/8)

    const size_t need = ((size_t)M * I + (size_t)O * I) * sizeof(u16);  // 64 MB
    if (ws_size >= need) {
        u16* At = (u16*)d_ws;
        u16* Bt = At + (size_t)M * I;
        prep_kernel<<<dim3(2048), THREADS, 0, stream>>>(x, pw, scale, pzp, At, Bt, M, O, I, ng, lsSeg, lsG);
        gemm_bf16<<<dim3((M / TILE) * (O / TILE)), THREADS, 0, stream>>>(At, Bt, bias, out, O, I, KT);
    } else {
        wql_fused<<<dim3((M / TILE) * (O / TILE)), THREADS, 0, stream>>>(x, pw, scale, pzp, bias, out, M, O, I, ng);
    }
}